// Round 12
// baseline (141.060 us; speedup 1.0000x reference)
//
#include <hip/hip_runtime.h>

// Mamba selective scan: BATCH=2, DIM=768, L=2048, N=16, fp32.
// R12: traffic-reduction round.
//  - p1 caches softplus(delta+bias) as bf16 (spg): p3 skips the delta read,
//    the softplus recompute, AND the delta LDS slab (29.7KB LDS).
//  - h/hI stored as bf16 (packed 2/u32): p1 store, p2 r/w, p3 read halve.
//    Safe: per-chunk decay ~2^-18 so bf16 rounding doesn't compound.
//  - Structure otherwise = R11 (3 kernels, u per-lane, B/C LDS-transposed).

#define LOG2E 1.4426950408889634f
#define LN2   0.6931471805599453f

constexpr int BATCH = 2, DIM = 768, L = 2048, N = 16;
constexpr int NC = 128, LC = 16;       // chunks, steps per chunk
constexpr int DG = DIM / 64;           // 12 d-groups
constexpr int CPB = 4;                 // chunks per block (1 per wave)
constexpr int CG = NC / CPB;           // 32 chunk-groups
constexpr int NBLK = BATCH * DG * CG;  // 768 blocks
constexpr int NCOMB = BATCH * DIM * N; // 24576 combine threads
constexpr int PAD = 76;                // 76 % 32 == 12 -> b128 conflict-free
static_assert(NC * LC == L, "chunking must cover L");

__device__ __forceinline__ float fexp2(float x) { return __builtin_amdgcn_exp2f(x); }
__device__ __forceinline__ float softplus(float v) {
  float s = LN2 * __log2f(1.0f + fexp2(v * LOG2E));
  return (v > 20.0f) ? v : s;
}
__device__ __forceinline__ float silu(float v) { return v / (1.0f + fexp2(-v * LOG2E)); }

// bf16 pack (RNE) / unpack helpers
__device__ __forceinline__ unsigned pack2bf(float a, float b) {
  unsigned ua = __float_as_uint(a), ub = __float_as_uint(b);
  unsigned ra = (ua + 0x7FFFu + ((ua >> 16) & 1u)) >> 16;
  unsigned rb = (ub + 0x7FFFu + ((ub >> 16) & 1u)) >> 16;
  return ra | (rb << 16);
}
__device__ __forceinline__ float lo_bf(unsigned p) { return __uint_as_float(p << 16); }
__device__ __forceinline__ float hi_bf(unsigned p) { return __uint_as_float(p & 0xFFFF0000u); }

// ---------------- pass 1 ----------------
__global__ __launch_bounds__(256, 6) void k_pass1(
    const float* __restrict__ u, const float* __restrict__ delta,
    const float* __restrict__ A, const float* __restrict__ dbias,
    const float* __restrict__ Bg, unsigned* __restrict__ h,
    unsigned* __restrict__ spg, float* __restrict__ S)
{
  __shared__ float ds_[64][PAD];   // delta, [d][l] transposed
  __shared__ float Bsr[64][20];    // B, [l][n] transposed

  const int bid = blockIdx.x, t = threadIdx.x;
  const int cgi = bid & 31;
  const int dgb = bid >> 5;
  const int dg = dgb % DG;
  const int b = dgb / DG;
  const int d0 = dg * 64, l0 = cgi * 64;

  const int w = t >> 6, lane = t & 63;
  const int c = cgi * CPB + w;
  const int d = d0 + lane;
  const int row16 = t >> 4;
  const int col4 = (t & 15) * 4;

  // u: per-lane direct (one 64B line per lane)
  const long ubase = ((long)(b * DIM + d)) * L + c * LC;
  float4 u0 = *(const float4*)(u + ubase + 0);
  float4 u1 = *(const float4*)(u + ubase + 4);
  float4 u2 = *(const float4*)(u + ubase + 8);
  float4 u3 = *(const float4*)(u + ubase + 12);

  // delta + B: coalesced staging
  float4 dreg[4];
#pragma unroll
  for (int rr = 0; rr < 4; rr++) {
    int row = row16 + rr * 16;
    long gof = ((long)(b * DIM + d0 + row)) * L + l0 + col4;
    dreg[rr] = *(const float4*)(delta + gof);
  }
  long bof = ((long)(b * N + row16)) * L + l0 + col4;
  float4 breg = *(const float4*)(Bg + bof);

  float A2[N];
#pragma unroll
  for (int q = 0; q < 4; q++) {
    float4 av = *(const float4*)(A + d * N + q * 4);
    A2[q*4+0] = av.x * LOG2E; A2[q*4+1] = av.y * LOG2E;
    A2[q*4+2] = av.z * LOG2E; A2[q*4+3] = av.w * LOG2E;
  }
  const float bias = dbias[d];

#pragma unroll
  for (int rr = 0; rr < 4; rr++) {
    int row = row16 + rr * 16;
    *(float4*)&ds_[row][col4] = dreg[rr];
  }
  Bsr[col4 + 0][row16] = breg.x;
  Bsr[col4 + 1][row16] = breg.y;
  Bsr[col4 + 2][row16] = breg.z;
  Bsr[col4 + 3][row16] = breg.w;

  float uu[LC];
  uu[0]=u0.x; uu[1]=u0.y; uu[2]=u0.z; uu[3]=u0.w;
  uu[4]=u1.x; uu[5]=u1.y; uu[6]=u1.z; uu[7]=u1.w;
  uu[8]=u2.x; uu[9]=u2.y; uu[10]=u2.z; uu[11]=u2.w;
  uu[12]=u3.x; uu[13]=u3.y; uu[14]=u3.z; uu[15]=u3.w;

  __syncthreads();

  float sp[LC], Ssum = 0.f;
#pragma unroll
  for (int q = 0; q < 4; q++) {
    float4 dv = *(const float4*)&ds_[lane][w * LC + q * 4];
    sp[q*4+0] = softplus(dv.x + bias);
    sp[q*4+1] = softplus(dv.y + bias);
    sp[q*4+2] = softplus(dv.z + bias);
    sp[q*4+3] = softplus(dv.w + bias);
  }
#pragma unroll
  for (int j = 0; j < LC; j++) Ssum += sp[j];

  // cache sp as bf16: 8 u32 per (c,d), contiguous 32B/lane
  const long sb8 = (((long)(b * NC + c)) * DIM + d) * 8;
  {
    uint4 w0, w1;
    w0.x = pack2bf(sp[0], sp[1]);  w0.y = pack2bf(sp[2], sp[3]);
    w0.z = pack2bf(sp[4], sp[5]);  w0.w = pack2bf(sp[6], sp[7]);
    w1.x = pack2bf(sp[8], sp[9]);  w1.y = pack2bf(sp[10], sp[11]);
    w1.z = pack2bf(sp[12], sp[13]); w1.w = pack2bf(sp[14], sp[15]);
    *(uint4*)(spg + sb8) = w0;
    *(uint4*)(spg + sb8 + 4) = w1;
  }

  float x[N];
#pragma unroll
  for (int n = 0; n < N; n++) x[n] = 0.f;
#pragma unroll
  for (int j = 0; j < LC; j++) {
    const int row = w * LC + j;
    float bb[16];
#pragma unroll
    for (int q = 0; q < 4; q++) {
      float4 bv = *(const float4*)&Bsr[row][q * 4];   // broadcast b128
      bb[q*4+0] = bv.x; bb[q*4+1] = bv.y; bb[q*4+2] = bv.z; bb[q*4+3] = bv.w;
    }
    float du = sp[j] * uu[j];
#pragma unroll
    for (int n = 0; n < N; n++) {
      float a = fexp2(sp[j] * A2[n]);
      x[n] = a * x[n] + du * bb[n];
    }
  }

  // h bf16 [b][c][d][n]: 8 u32 contiguous per lane
  {
    uint4 w0, w1;
    w0.x = pack2bf(x[0], x[1]);   w0.y = pack2bf(x[2], x[3]);
    w0.z = pack2bf(x[4], x[5]);   w0.w = pack2bf(x[6], x[7]);
    w1.x = pack2bf(x[8], x[9]);   w1.y = pack2bf(x[10], x[11]);
    w1.z = pack2bf(x[12], x[13]); w1.w = pack2bf(x[14], x[15]);
    *(uint4*)(h + sb8) = w0;
    *(uint4*)(h + sb8 + 4) = w1;
  }
  S[(b * NC + c) * DIM + d] = Ssum;
}

// ---------------- pass 2: combine (bf16 h/hI), no alias, batched ----------------
__global__ __launch_bounds__(128) void k_pass2(
    const unsigned* __restrict__ h, const float* __restrict__ S,
    const float* __restrict__ A, unsigned* __restrict__ hI)
{
  int g = blockIdx.x * 128 + threadIdx.x;   // g = (bb*768 + dd)*16 + n
  int n = g & 15;
  int r = g >> 4;
  int dd = r % DIM;
  int bb = r / DIM;
  const float a2 = A[dd * N + n] * LOG2E;
  const unsigned short* hs = (const unsigned short*)h;
  unsigned short* hIs = (unsigned short*)hI;
  const long step = (long)DIM * 16;
  const long base0 = (((long)bb * NC) * DIM + dd) * 16 + n;
  const long sbase = (long)(bb * NC) * DIM + dd;

  float x = 0.f;
  for (int cb = 0; cb < NC / 16; cb++) {
    float hc[16], Sc[16];
#pragma unroll
    for (int k = 0; k < 16; k++) {
      unsigned short hv = hs[base0 + (long)(cb * 16 + k) * step];
      hc[k] = __uint_as_float(((unsigned)hv) << 16);
      Sc[k] = S[sbase + (long)(cb * 16 + k) * DIM];
    }
#pragma unroll
    for (int k = 0; k < 16; k++) {
      unsigned ux = __float_as_uint(x);
      hIs[base0 + (long)(cb * 16 + k) * step] =
          (unsigned short)((ux + 0x7FFFu + ((ux >> 16) & 1u)) >> 16);
      x = fexp2(Sc[k] * a2) * x + hc[k];
    }
  }
}

// ---------------- pass 3 ----------------
__global__ __launch_bounds__(256, 4) void k_pass3(
    const float* __restrict__ u, const float* __restrict__ A,
    const float* __restrict__ Bg, const float* __restrict__ Cg,
    const float* __restrict__ Dv, const float* __restrict__ z,
    const unsigned* __restrict__ xinit, const unsigned* __restrict__ spg,
    float* __restrict__ out)
{
  __shared__ float ys[64][PAD];    // y slab (for coalesced epilogue)
  __shared__ float Bsr[64][20];
  __shared__ float Csr[64][20];

  const int bid = blockIdx.x, t = threadIdx.x;
  const int cgi = bid & 31;
  const int dgb = bid >> 5;
  const int dg = dgb % DG;
  const int b = dgb / DG;
  const int d0 = dg * 64, l0 = cgi * 64;

  const int w = t >> 6, lane = t & 63;
  const int c = cgi * CPB + w;
  const int d = d0 + lane;
  const int row16 = t >> 4;
  const int col4 = (t & 15) * 4;

  // u per-lane direct; sp + x_init per-lane bf16 (32B each)
  const long ubase = ((long)(b * DIM + d)) * L + c * LC;
  float4 u0 = *(const float4*)(u + ubase + 0);
  float4 u1 = *(const float4*)(u + ubase + 4);
  float4 u2 = *(const float4*)(u + ubase + 8);
  float4 u3 = *(const float4*)(u + ubase + 12);

  const long sb8 = (((long)(b * NC + c)) * DIM + d) * 8;
  uint4 sp0 = *(const uint4*)(spg + sb8);
  uint4 sp1 = *(const uint4*)(spg + sb8 + 4);
  uint4 xi0 = *(const uint4*)(xinit + sb8);
  uint4 xi1 = *(const uint4*)(xinit + sb8 + 4);

  // B + C + z: coalesced
  float4 zreg[4];
#pragma unroll
  for (int rr = 0; rr < 4; rr++) {
    int row = row16 + rr * 16;
    long gof = ((long)(b * DIM + d0 + row)) * L + l0 + col4;
    zreg[rr] = *(const float4*)(z + gof);
  }
  long bof = ((long)(b * N + row16)) * L + l0 + col4;
  float4 breg = *(const float4*)(Bg + bof);
  float4 creg = *(const float4*)(Cg + bof);

  float A2[N];
#pragma unroll
  for (int q = 0; q < 4; q++) {
    float4 av = *(const float4*)(A + d * N + q * 4);
    A2[q*4+0] = av.x * LOG2E; A2[q*4+1] = av.y * LOG2E;
    A2[q*4+2] = av.z * LOG2E; A2[q*4+3] = av.w * LOG2E;
  }

  Bsr[col4 + 0][row16] = breg.x;
  Bsr[col4 + 1][row16] = breg.y;
  Bsr[col4 + 2][row16] = breg.z;
  Bsr[col4 + 3][row16] = breg.w;
  Csr[col4 + 0][row16] = creg.x;
  Csr[col4 + 1][row16] = creg.y;
  Csr[col4 + 2][row16] = creg.z;
  Csr[col4 + 3][row16] = creg.w;

  float uu[LC];
  uu[0]=u0.x; uu[1]=u0.y; uu[2]=u0.z; uu[3]=u0.w;
  uu[4]=u1.x; uu[5]=u1.y; uu[6]=u1.z; uu[7]=u1.w;
  uu[8]=u2.x; uu[9]=u2.y; uu[10]=u2.z; uu[11]=u2.w;
  uu[12]=u3.x; uu[13]=u3.y; uu[14]=u3.z; uu[15]=u3.w;

  float sp[LC];
  sp[0]=lo_bf(sp0.x); sp[1]=hi_bf(sp0.x); sp[2]=lo_bf(sp0.y); sp[3]=hi_bf(sp0.y);
  sp[4]=lo_bf(sp0.z); sp[5]=hi_bf(sp0.z); sp[6]=lo_bf(sp0.w); sp[7]=hi_bf(sp0.w);
  sp[8]=lo_bf(sp1.x); sp[9]=hi_bf(sp1.x); sp[10]=lo_bf(sp1.y); sp[11]=hi_bf(sp1.y);
  sp[12]=lo_bf(sp1.z); sp[13]=hi_bf(sp1.z); sp[14]=lo_bf(sp1.w); sp[15]=hi_bf(sp1.w);

  float x[N];
  x[0]=lo_bf(xi0.x); x[1]=hi_bf(xi0.x); x[2]=lo_bf(xi0.y); x[3]=hi_bf(xi0.y);
  x[4]=lo_bf(xi0.z); x[5]=hi_bf(xi0.z); x[6]=lo_bf(xi0.w); x[7]=hi_bf(xi0.w);
  x[8]=lo_bf(xi1.x); x[9]=hi_bf(xi1.x); x[10]=lo_bf(xi1.y); x[11]=hi_bf(xi1.y);
  x[12]=lo_bf(xi1.z); x[13]=hi_bf(xi1.z); x[14]=lo_bf(xi1.w); x[15]=hi_bf(xi1.w);

  __syncthreads();   // Bsr/Csr ready

  float y[LC];
#pragma unroll
  for (int j = 0; j < LC; j++) {
    const int row = w * LC + j;
    float bb[16], ccv[16];
#pragma unroll
    for (int q = 0; q < 4; q++) {
      float4 bv = *(const float4*)&Bsr[row][q * 4];   // broadcast b128
      float4 cv = *(const float4*)&Csr[row][q * 4];
      bb[q*4+0] = bv.x; bb[q*4+1] = bv.y; bb[q*4+2] = bv.z; bb[q*4+3] = bv.w;
      ccv[q*4+0] = cv.x; ccv[q*4+1] = cv.y; ccv[q*4+2] = cv.z; ccv[q*4+3] = cv.w;
    }
    float du = sp[j] * uu[j];
    float acc = 0.f;
#pragma unroll
    for (int n = 0; n < N; n++) {
      float a = fexp2(sp[j] * A2[n]);
      x[n] = a * x[n] + du * bb[n];
      acc += x[n] * ccv[n];
    }
    y[j] = acc;
  }

#pragma unroll
  for (int q = 0; q < 4; q++) {
    float4 v; v.x = y[q*4+0]; v.y = y[q*4+1]; v.z = y[q*4+2]; v.w = y[q*4+3];
    *(float4*)&ys[lane][w * LC + q * 4] = v;
  }

  __syncthreads();

  // coalesced epilogue: out = (y + u*D) * silu(z); u re-read (L1/L2-hot)
#pragma unroll
  for (int rr = 0; rr < 4; rr++) {
    int row = row16 + rr * 16;
    long gof = ((long)(b * DIM + d0 + row)) * L + l0 + col4;
    float4 zv = zreg[rr];
    float4 uv = *(const float4*)(u + gof);
    float4 yv = *(const float4*)&ys[row][col4];
    float Dd2 = Dv[d0 + row];
    float4 ov;
    ov.x = (yv.x + uv.x * Dd2) * silu(zv.x);
    ov.y = (yv.y + uv.y * Dd2) * silu(zv.y);
    ov.z = (yv.z + uv.z * Dd2) * silu(zv.z);
    ov.w = (yv.w + uv.w * Dd2) * silu(zv.w);
    *(float4*)(out + gof) = ov;
  }
}

// ---------------- fallback (ws too small) ----------------
__global__ __launch_bounds__(256) void k_simple(
    const float* __restrict__ u, const float* __restrict__ delta,
    const float* __restrict__ A, const float* __restrict__ dbias,
    const float* __restrict__ Bm, const float* __restrict__ Cm,
    const float* __restrict__ Dv, const float* __restrict__ z,
    float* __restrict__ out) {
  int t = blockIdx.x * 256 + threadIdx.x;
  int n = t % N;
  int bd = t / N;
  int d = bd % DIM;
  int b = bd / DIM;
  float A2 = A[d * N + n] * LOG2E;
  float bias = dbias[d];
  float Dd = Dv[d];
  const float* Bp = Bm + ((long)b * N + n) * L;
  const float* Cp = Cm + ((long)b * N + n) * L;
  long base = (long)bd * L;
  float x = 0.0f;
  for (int l = 0; l < L; l++) {
    float dv = delta[base + l];
    float uv = u[base + l];
    float sp = softplus(dv + bias);
    float a = fexp2(sp * A2);
    x = a * x + sp * uv * Bp[l];
    float y = x * Cp[l];
#pragma unroll
    for (int off = 8; off; off >>= 1) y += __shfl_xor(y, off, 16);
    if (n == 0) {
      float zv = z[base + l];
      out[base + l] = (y + uv * Dd) * silu(zv);
    }
  }
}

extern "C" void kernel_launch(void* const* d_in, const int* in_sizes, int n_in,
                              void* d_out, int out_size, void* d_ws, size_t ws_size,
                              hipStream_t stream) {
  const float* u     = (const float*)d_in[0];
  const float* delta = (const float*)d_in[1];
  const float* A     = (const float*)d_in[2];
  const float* Bm    = (const float*)d_in[3];
  const float* Cm    = (const float*)d_in[4];
  const float* Dv    = (const float*)d_in[5];
  const float* z     = (const float*)d_in[6];
  const float* dbias = (const float*)d_in[7];
  float* out = (float*)d_out;

  const size_t hp8 = (size_t)BATCH * NC * DIM * 8;  // u32 count per bf16 16-pack array
  const size_t spn = (size_t)BATCH * NC * DIM;      // S floats
  const size_t need = (3 * hp8 + spn) * sizeof(unsigned);

  if (ws_size < need) {
    k_simple<<<(BATCH * DIM * N) / 256, 256, 0, stream>>>(u, delta, A, dbias, Bm, Cm, Dv, z, out);
    return;
  }

  unsigned* h   = (unsigned*)d_ws;
  unsigned* hI  = h + hp8;
  unsigned* spg = hI + hp8;
  float* S      = (float*)(spg + hp8);

  k_pass1<<<NBLK, 256, 0, stream>>>(u, delta, A, dbias, Bm, h, spg, S);
  k_pass2<<<NCOMB / 128, 128, 0, stream>>>(h, S, A, hI);
  k_pass3<<<NBLK, 256, 0, stream>>>(u, A, Bm, Cm, Dv, z, hI, spg, out);
}